// Round 4
// baseline (281.965 us; speedup 1.0000x reference)
//
#include <hip/hip_runtime.h>
#include <hip/hip_bf16.h>

// HoloAttention: out = (Re(cumsum_t(x@Wv^T * e^{i t f}) * e^{-i t f})) @ Wo^T
// (k-projection in reference is dead code — skipped.)
//
// R4: GEMM LDS XOR-swizzle (global-side permutation, kills 8-way ds_read_b128
// bank conflicts); scan passes at 16 B/lane (8 d's/thread, uint4), CS=32,
// batched loads for 8 outstanding per lane.

#define B_  2
#define T_  8192
#define D_  1024
#define BT_ 16384
#define CS_ 32
#define NCHUNK_ 256

typedef __attribute__((ext_vector_type(4))) float f32x4;
typedef __attribute__((ext_vector_type(8))) short bf16x8;

static __device__ inline unsigned short f2bf(float f) {
    union { float f; unsigned int u; } a;
    a.f = f;
    unsigned int u = a.u;
    return (unsigned short)((u + 0x7FFFu + ((u >> 16) & 1u)) >> 16);  // RNE
}
static __device__ inline float bf2f(unsigned short h) {
    union { unsigned int u; float f; } a;
    a.u = ((unsigned int)h) << 16;
    return a.f;
}
// LDS column swizzle: slot (row, c4) holds global 8-col block (c4 ^ fsw(row)).
// Bank-group of a fragment read becomes (4r + c4^fsw(r)) % 8 -> perfect 2-way
// spread over 16 consecutive rows (2-way is free per m136).
static __device__ inline int fsw(int r) { return ((r & 3) + ((r >> 2) & 3)) & 3; }

// One fused cast: x (4194304 float4) | Wv (262144) | Wo (262144)
__global__ __launch_bounds__(256) void cast_all(const float* __restrict__ x,
                                                const float* __restrict__ Wv,
                                                const float* __restrict__ Wo,
                                                unsigned short* __restrict__ xb,
                                                unsigned short* __restrict__ wvb,
                                                unsigned short* __restrict__ wob) {
    const int nx = BT_ * D_ / 4;
    const int nw = D_ * D_ / 4;
    int i = blockIdx.x * 256 + threadIdx.x;
    const float4* src;
    unsigned short* dst;
    int j;
    if (i < nx)            { src = (const float4*)x;  dst = xb;  j = i; }
    else if (i < nx + nw)  { src = (const float4*)Wv; dst = wvb; j = i - nx; }
    else                   { src = (const float4*)Wo; dst = wob; j = i - nx - nw; }
    float4 v = src[j];
    ushort4 o;
    o.x = f2bf(v.x); o.y = f2bf(v.y); o.z = f2bf(v.z); o.w = f2bf(v.w);
    ((ushort4*)dst)[j] = o;
}

// C[M,N] = A[M,K] (bf16 row-major) @ Bm[N,K]^T (bf16 row-major).
// 4 waves (2x2), wave tile 64x64 (4x4 mfma 16x16x32), block tile 128x128,
// BK=32, LDS staging via global_load_lds width=16 (m97 structure),
// XCD-swizzled 1-D grid, XOR'd LDS columns.
template <bool BF16OUT>
__global__ __launch_bounds__(256) void gemm_bt(const short* __restrict__ A,
                                               const short* __restrict__ Bm,
                                               void* __restrict__ Cout,
                                               int M, int N, int K) {
    __shared__ short lds[8192];  // A tile: shorts [0,4096), B tile: [4096,8192)
    const int lane = threadIdx.x & 63;
    const int wave = threadIdx.x >> 6;
    const int wr = wave >> 1, wc = wave & 1;

    const int nb = N >> 7;              // N-blocks (8)
    const int id = blockIdx.x;
    const int xcd = id & 7;
    const int slot = id >> 3;
    const int bn = (slot % nb) * 128;
    const int bm = (xcd * ((M >> 7) >> 3) + slot / nb) * 128;

    // staging map: chunk = 16 rows x 32 cols = 1024 B; lane -> (row, 8-col block)
    const int r0 = lane >> 2;   // 0..15
    const int cb = lane & 3;    // 0..3

    // hoisted staging pointers (global side carries the swizzle)
    const short* ga[2];
    const short* gb[2];
#pragma unroll
    for (int cc = 0; cc < 2; ++cc) {
        const int chunk = wave * 2 + cc;
        const int row = chunk * 16 + r0;
        const int col = (cb ^ fsw(row)) * 8;
        ga[cc] = A + (size_t)(bm + row) * K + col;
        gb[cc] = Bm + (size_t)(bn + row) * K + col;
    }

    // hoisted fragment read offsets (k-invariant; swizzled)
    const int c4r = lane >> 4;  // 0..3
    int aoff[4], boff[4];
#pragma unroll
    for (int i = 0; i < 4; ++i) {
        const int m = wr * 64 + (lane & 15) + i * 16;
        aoff[i] = m * 32 + ((c4r ^ fsw(m)) * 8);
        const int n = wc * 64 + (lane & 15) + i * 16;
        boff[i] = 4096 + n * 32 + ((c4r ^ fsw(n)) * 8);
    }

    f32x4 acc[4][4] = {};

    for (int k0 = 0; k0 < K; k0 += 32) {
#pragma unroll
        for (int cc = 0; cc < 2; ++cc) {
            const int chunk = wave * 2 + cc;
            __builtin_amdgcn_global_load_lds(
                (const __attribute__((address_space(1))) void*)(ga[cc] + k0),
                (__attribute__((address_space(3))) void*)&lds[chunk * 512], 16, 0, 0);
            __builtin_amdgcn_global_load_lds(
                (const __attribute__((address_space(1))) void*)(gb[cc] + k0),
                (__attribute__((address_space(3))) void*)&lds[4096 + chunk * 512], 16, 0, 0);
        }
        __syncthreads();
        bf16x8 a[4], b[4];
#pragma unroll
        for (int i = 0; i < 4; ++i) a[i] = *(const bf16x8*)&lds[aoff[i]];
#pragma unroll
        for (int j = 0; j < 4; ++j) b[j] = *(const bf16x8*)&lds[boff[j]];
#pragma unroll
        for (int i = 0; i < 4; ++i)
#pragma unroll
            for (int j = 0; j < 4; ++j)
                acc[i][j] = __builtin_amdgcn_mfma_f32_16x16x32_bf16(a[i], b[j], acc[i][j], 0, 0, 0);
        __syncthreads();
    }

    const int row0 = (lane >> 4) * 4;
#pragma unroll
    for (int i = 0; i < 4; ++i) {
#pragma unroll
        for (int j = 0; j < 4; ++j) {
            const int col = bn + wc * 64 + j * 16 + (lane & 15);
#pragma unroll
            for (int r = 0; r < 4; ++r) {
                const size_t row = bm + wr * 64 + i * 16 + row0 + r;
                if constexpr (BF16OUT)
                    ((unsigned short*)Cout)[row * N + col] = f2bf(acc[i][j][r]);
                else
                    ((float*)Cout)[row * N + col] = acc[i][j][r];
            }
        }
    }
}

// Pass 1: per-chunk complex sums of w_t = v_t * e^{i t f}; 8 d's per thread,
// uint4 (16 B) loads, inner loop batched by 8 rows.
__global__ __launch_bounds__(256) void scan_pass1(const unsigned short* __restrict__ v,
                                                  const float* __restrict__ freqs,
                                                  float* __restrict__ csum) {
    const int tid = threadIdx.x;
    const int chunk = blockIdx.x * 2 + (tid >> 7);
    const int b = blockIdx.y;
    const int d0 = (tid & 127) * 8;

    float fr[8], s[8], c[8], sf[8], cf[8], ar[8] = {}, ai[8] = {};
    {
        float4 fA = *(const float4*)(freqs + d0);
        float4 fB = *(const float4*)(freqs + d0 + 4);
        fr[0] = fA.x; fr[1] = fA.y; fr[2] = fA.z; fr[3] = fA.w;
        fr[4] = fB.x; fr[5] = fB.y; fr[6] = fB.z; fr[7] = fB.w;
    }
    const float t0f = (float)(chunk * CS_);
#pragma unroll
    for (int k = 0; k < 8; ++k) {
        sincosf(t0f * fr[k], &s[k], &c[k]);
        sincosf(fr[k], &sf[k], &cf[k]);
    }
    const uint4* vp = (const uint4*)(v + ((size_t)b * T_ + chunk * CS_) * D_ + d0);
    for (int tb = 0; tb < CS_; tb += 8) {
        uint4 w[8];
#pragma unroll
        for (int u = 0; u < 8; ++u) w[u] = vp[(size_t)(tb + u) * (D_ / 8)];
#pragma unroll
        for (int u = 0; u < 8; ++u) {
            const unsigned int wd[4] = {w[u].x, w[u].y, w[u].z, w[u].w};
#pragma unroll
            for (int k = 0; k < 8; ++k) {
                float wv = bf2f((unsigned short)(wd[k >> 1] >> ((k & 1) * 16)));
                ar[k] = fmaf(wv, c[k], ar[k]);
                ai[k] = fmaf(wv, s[k], ai[k]);
                float nc = c[k] * cf[k] - s[k] * sf[k];
                float ns = s[k] * cf[k] + c[k] * sf[k];
                c[k] = nc; s[k] = ns;
            }
        }
    }
    float4* cp = (float4*)(csum + (((size_t)b * NCHUNK_ + chunk) * D_ + d0) * 2);
#pragma unroll
    for (int k = 0; k < 4; ++k) {
        float4 o; o.x = ar[2 * k]; o.y = ai[2 * k]; o.z = ar[2 * k + 1]; o.w = ai[2 * k + 1];
        cp[k] = o;
    }
}

// Pass 2: exclusive prefix of chunk sums per (b,d), batched loads (latency).
__global__ __launch_bounds__(256) void scan_pass2(float* __restrict__ csum) {
    const int g = blockIdx.x * 256 + threadIdx.x;  // 0 .. B*D-1
    const int b = g / D_;
    const int d = g % D_;
    float2* cs = (float2*)csum;
    const size_t base = (size_t)b * NCHUNK_ * D_ + d;
    float pr = 0.f, pi = 0.f;
    for (int cc = 0; cc < NCHUNK_; cc += 16) {
        float2 buf[16];
#pragma unroll
        for (int k = 0; k < 16; ++k) buf[k] = cs[base + (size_t)(cc + k) * D_];
#pragma unroll
        for (int k = 0; k < 16; ++k) {
            float r = buf[k].x, im = buf[k].y;
            buf[k] = make_float2(pr, pi);
            pr += r; pi += im;
        }
#pragma unroll
        for (int k = 0; k < 16; ++k) cs[base + (size_t)(cc + k) * D_] = buf[k];
    }
}

// Pass 3: replay chunk; retrieved = Re(mt * conj(rotor)) -> bf16; 8 d's/thread.
__global__ __launch_bounds__(256) void scan_pass3(const unsigned short* __restrict__ v,
                                                  const float* __restrict__ freqs,
                                                  const float* __restrict__ csum,
                                                  unsigned short* __restrict__ ret) {
    const int tid = threadIdx.x;
    const int chunk = blockIdx.x * 2 + (tid >> 7);
    const int b = blockIdx.y;
    const int d0 = (tid & 127) * 8;

    float fr[8], s[8], c[8], sf[8], cf[8], ar[8], ai[8];
    {
        float4 fA = *(const float4*)(freqs + d0);
        float4 fB = *(const float4*)(freqs + d0 + 4);
        fr[0] = fA.x; fr[1] = fA.y; fr[2] = fA.z; fr[3] = fA.w;
        fr[4] = fB.x; fr[5] = fB.y; fr[6] = fB.z; fr[7] = fB.w;
    }
    const float t0f = (float)(chunk * CS_);
#pragma unroll
    for (int k = 0; k < 8; ++k) {
        sincosf(t0f * fr[k], &s[k], &c[k]);
        sincosf(fr[k], &sf[k], &cf[k]);
    }
    {
        const float4* cp = (const float4*)(csum + (((size_t)b * NCHUNK_ + chunk) * D_ + d0) * 2);
#pragma unroll
        for (int k = 0; k < 4; ++k) {
            float4 o = cp[k];
            ar[2 * k] = o.x; ai[2 * k] = o.y; ar[2 * k + 1] = o.z; ai[2 * k + 1] = o.w;
        }
    }
    const uint4* vp = (const uint4*)(v + ((size_t)b * T_ + chunk * CS_) * D_ + d0);
    uint4* rp = (uint4*)(ret + ((size_t)b * T_ + chunk * CS_) * D_ + d0);
    for (int tb = 0; tb < CS_; tb += 8) {
        uint4 w[8];
#pragma unroll
        for (int u = 0; u < 8; ++u) w[u] = vp[(size_t)(tb + u) * (D_ / 8)];
#pragma unroll
        for (int u = 0; u < 8; ++u) {
            const unsigned int wd[4] = {w[u].x, w[u].y, w[u].z, w[u].w};
            unsigned int od[4];
#pragma unroll
            for (int k = 0; k < 8; k += 2) {
                float w0 = bf2f((unsigned short)(wd[k >> 1]));
                float w1 = bf2f((unsigned short)(wd[k >> 1] >> 16));
                ar[k] = fmaf(w0, c[k], ar[k]); ai[k] = fmaf(w0, s[k], ai[k]);
                ar[k + 1] = fmaf(w1, c[k + 1], ar[k + 1]); ai[k + 1] = fmaf(w1, s[k + 1], ai[k + 1]);
                float o0 = ar[k] * c[k] + ai[k] * s[k];
                float o1 = ar[k + 1] * c[k + 1] + ai[k + 1] * s[k + 1];
                od[k >> 1] = (unsigned int)f2bf(o0) | ((unsigned int)f2bf(o1) << 16);
#pragma unroll
                for (int q = 0; q < 2; ++q) {
                    float nc = c[k + q] * cf[k + q] - s[k + q] * sf[k + q];
                    float ns = s[k + q] * cf[k + q] + c[k + q] * sf[k + q];
                    c[k + q] = nc; s[k + q] = ns;
                }
            }
            uint4 o4; o4.x = od[0]; o4.y = od[1]; o4.z = od[2]; o4.w = od[3];
            rp[(size_t)(tb + u) * (D_ / 8)] = o4;
        }
    }
}

extern "C" void kernel_launch(void* const* d_in, const int* in_sizes, int n_in,
                              void* d_out, int out_size, void* d_ws, size_t ws_size,
                              hipStream_t stream) {
    const float* x     = (const float*)d_in[0];
    // d_in[1] = Wk (dead in reference)
    const float* Wv    = (const float*)d_in[2];
    const float* Wo    = (const float*)d_in[3];
    const float* freqs = (const float*)d_in[4];
    float* out = (float*)d_out;

    char* ws = (char*)d_ws;
    unsigned short* x_bf  = (unsigned short*)ws;                 // 33,554,432 B
    unsigned short* Wv_bf = (unsigned short*)(ws + 33554432);    //  2,097,152 B
    unsigned short* Wo_bf = (unsigned short*)(ws + 35651584);    //  2,097,152 B
    unsigned short* ret   = (unsigned short*)(ws + 37748736);    // 33,554,432 B
    float*          csum  = (float*)(ws + 71303168);             //  4,194,304 B (B*256*D*2*4)
    // v (bf16) lives in d_out's first half; dead before GEMM2 overwrites d_out.
    unsigned short* v_bf = (unsigned short*)d_out;

    // 1. fused casts (x | Wv | Wo)
    cast_all<<<(BT_ * D_ / 4 + 2 * D_ * D_ / 4) / 256, 256, 0, stream>>>(
        x, Wv, Wo, x_bf, Wv_bf, Wo_bf);

    // 2. v = x @ Wv^T  (bf16 out), XCD-swizzled 1-D grid
    gemm_bt<true><<<(BT_ / 128) * (D_ / 128), 256, 0, stream>>>(
        (const short*)x_bf, (const short*)Wv_bf, (void*)v_bf, BT_, D_, D_);

    // 3. blocked rotor scan
    dim3 sgrid(NCHUNK_ / 2, B_);
    scan_pass1<<<sgrid, 256, 0, stream>>>(v_bf, freqs, csum);
    scan_pass2<<<(B_ * D_) / 256, 256, 0, stream>>>(csum);
    scan_pass3<<<sgrid, 256, 0, stream>>>(v_bf, freqs, csum, ret);

    // 4. out = retrieved @ Wo^T (fp32 out), XCD-swizzled 1-D grid
    gemm_bt<false><<<(BT_ / 128) * (D_ / 128), 256, 0, stream>>>(
        (const short*)ret, (const short*)Wo_bf, (void*)out, BT_, D_, D_);
}

// Round 5
// 257.332 us; speedup vs baseline: 1.0957x; 1.0957x over previous
//
#include <hip/hip_runtime.h>
#include <hip/hip_bf16.h>

// HoloAttention: out = (Re(cumsum_t(x@Wv^T * e^{i t f}) * e^{-i t f})) @ Wo^T
// (k-projection in reference is dead code — skipped.)
//
// R5: GEMM BK=64 (half the barrier drains, 32 MFMA/barrier-pair, XOR-swizzled
// LDS reads); scan passes back to 2048 waves, 4 d's/thread uint2, 8-row
// batches, low register pressure. NOTE: SQ_LDS_BANK_CONFLICT==8/global_load_lds
// is the structural write-drain, not a real conflict — ignore it.

#define B_  2
#define T_  8192
#define D_  1024
#define BT_ 16384
#define CS_ 32
#define NCHUNK_ 256

typedef __attribute__((ext_vector_type(4))) float f32x4;
typedef __attribute__((ext_vector_type(8))) short bf16x8;

static __device__ inline unsigned short f2bf(float f) {
    union { float f; unsigned int u; } a;
    a.f = f;
    unsigned int u = a.u;
    return (unsigned short)((u + 0x7FFFu + ((u >> 16) & 1u)) >> 16);  // RNE
}
static __device__ inline float bf2f(unsigned short h) {
    union { unsigned int u; float f; } a;
    a.u = ((unsigned int)h) << 16;
    return a.f;
}

// One fused cast: x (4194304 float4) | Wv (262144) | Wo (262144)
__global__ __launch_bounds__(256) void cast_all(const float* __restrict__ x,
                                                const float* __restrict__ Wv,
                                                const float* __restrict__ Wo,
                                                unsigned short* __restrict__ xb,
                                                unsigned short* __restrict__ wvb,
                                                unsigned short* __restrict__ wob) {
    const int nx = BT_ * D_ / 4;
    const int nw = D_ * D_ / 4;
    int i = blockIdx.x * 256 + threadIdx.x;
    const float4* src;
    unsigned short* dst;
    int j;
    if (i < nx)            { src = (const float4*)x;  dst = xb;  j = i; }
    else if (i < nx + nw)  { src = (const float4*)Wv; dst = wvb; j = i - nx; }
    else                   { src = (const float4*)Wo; dst = wob; j = i - nx - nw; }
    float4 v = src[j];
    ushort4 o;
    o.x = f2bf(v.x); o.y = f2bf(v.y); o.z = f2bf(v.z); o.w = f2bf(v.w);
    ((ushort4*)dst)[j] = o;
}

// C[M,N] = A[M,K] (bf16 row-major) @ Bm[N,K]^T (bf16 row-major).
// 4 waves (2x2), wave tile 64x64 (4x4 mfma 16x16x32), block tile 128x128,
// BK=64 (32 KB LDS), global_load_lds width=16, XCD-swizzled 1-D grid.
// LDS cols XOR-swizzled on the global side: slot (row, cb) holds global
// 8-col block (cb ^ (row&7)) -> fragment ds_read_b128 is a 2-way spread
// (free); unswizzled BK=64 rows are 128 B = exact bank wrap (16-way).
template <bool BF16OUT>
__global__ __launch_bounds__(256) void gemm_bt(const short* __restrict__ A,
                                               const short* __restrict__ Bm,
                                               void* __restrict__ Cout,
                                               int M, int N, int K) {
    __shared__ short lds[16384];  // A tile shorts [0,8192), B tile [8192,16384)
    const int lane = threadIdx.x & 63;
    const int wave = threadIdx.x >> 6;
    const int wr = wave >> 1, wc = wave & 1;

    const int nb = N >> 7;              // N-blocks (8)
    const int id = blockIdx.x;
    const int xcd = id & 7;
    const int slot = id >> 3;
    const int bn = (slot % nb) * 128;
    const int bm = (xcd * ((M >> 7) >> 3) + slot / nb) * 128;

    // staging: 16 chunks of 1 KB per matrix (chunk = 8 rows x 64 cols);
    // per wave 4 chunks of A + 4 of B. lane -> row = chunk*8 + (lane>>3),
    // col-block cb = lane&7 (8 shorts each).
    const int sr = lane >> 3;   // 0..7
    const int cb = lane & 7;    // 0..7
    const short* ga[4];
    const short* gb[4];
#pragma unroll
    for (int cc = 0; cc < 4; ++cc) {
        const int chunk = wave * 4 + cc;        // 0..15
        const int row = chunk * 8 + sr;         // 0..127
        const int col = (cb ^ (row & 7)) * 8;   // swizzled source col-block
        ga[cc] = A + (size_t)(bm + row) * K + col;
        gb[cc] = Bm + (size_t)(bn + row) * K + col;
    }

    // fragment read offsets (k0-invariant, swizzled): global k-block j = ks*4+c4r
    const int c4r = lane >> 4;  // 0..3
    int aoff[4][2], boff[4][2];
#pragma unroll
    for (int i = 0; i < 4; ++i) {
        const int m = wr * 64 + (lane & 15) + i * 16;
        const int n = wc * 64 + (lane & 15) + i * 16;
#pragma unroll
        for (int ks = 0; ks < 2; ++ks) {
            aoff[i][ks] = m * 64 + (((ks * 4 + c4r) ^ (m & 7)) * 8);
            boff[i][ks] = 8192 + n * 64 + (((ks * 4 + c4r) ^ (n & 7)) * 8);
        }
    }

    f32x4 acc[4][4] = {};

    for (int k0 = 0; k0 < K; k0 += 64) {
#pragma unroll
        for (int cc = 0; cc < 4; ++cc) {
            const int chunk = wave * 4 + cc;
            __builtin_amdgcn_global_load_lds(
                (const __attribute__((address_space(1))) void*)(ga[cc] + k0),
                (__attribute__((address_space(3))) void*)&lds[chunk * 512], 16, 0, 0);
            __builtin_amdgcn_global_load_lds(
                (const __attribute__((address_space(1))) void*)(gb[cc] + k0),
                (__attribute__((address_space(3))) void*)&lds[8192 + chunk * 512], 16, 0, 0);
        }
        __syncthreads();
#pragma unroll
        for (int ks = 0; ks < 2; ++ks) {
            bf16x8 a[4], b[4];
#pragma unroll
            for (int i = 0; i < 4; ++i) a[i] = *(const bf16x8*)&lds[aoff[i][ks]];
#pragma unroll
            for (int j = 0; j < 4; ++j) b[j] = *(const bf16x8*)&lds[boff[j][ks]];
#pragma unroll
            for (int i = 0; i < 4; ++i)
#pragma unroll
                for (int j = 0; j < 4; ++j)
                    acc[i][j] = __builtin_amdgcn_mfma_f32_16x16x32_bf16(a[i], b[j], acc[i][j], 0, 0, 0);
        }
        __syncthreads();
    }

    const int row0 = (lane >> 4) * 4;
#pragma unroll
    for (int i = 0; i < 4; ++i) {
#pragma unroll
        for (int j = 0; j < 4; ++j) {
            const int col = bn + wc * 64 + j * 16 + (lane & 15);
#pragma unroll
            for (int r = 0; r < 4; ++r) {
                const size_t row = bm + wr * 64 + i * 16 + row0 + r;
                if constexpr (BF16OUT)
                    ((unsigned short*)Cout)[row * N + col] = f2bf(acc[i][j][r]);
                else
                    ((float*)Cout)[row * N + col] = acc[i][j][r];
            }
        }
    }
}

// Pass 1: per-chunk complex sums of w_t = v_t * e^{i t f}; 4 d's/thread,
// uint2 (8 B) coalesced loads, 8-row batches, grid (NCHUNK, B) = 2048 waves.
__global__ __launch_bounds__(256) void scan_pass1(const unsigned short* __restrict__ v,
                                                  const float* __restrict__ freqs,
                                                  float* __restrict__ csum) {
    const int d0 = threadIdx.x * 4;
    const int chunk = blockIdx.x;
    const int b = blockIdx.y;

    float fr[4], s[4], c[4], sf[4], cf[4], ar[4] = {}, ai[4] = {};
    {
        float4 f4 = *(const float4*)(freqs + d0);
        fr[0] = f4.x; fr[1] = f4.y; fr[2] = f4.z; fr[3] = f4.w;
    }
    const float t0f = (float)(chunk * CS_);
#pragma unroll
    for (int k = 0; k < 4; ++k) {
        sincosf(t0f * fr[k], &s[k], &c[k]);
        sincosf(fr[k], &sf[k], &cf[k]);
    }
    const uint2* vp = (const uint2*)(v + ((size_t)b * T_ + chunk * CS_) * D_ + d0);
    for (int tb = 0; tb < CS_; tb += 8) {
        uint2 w[8];
#pragma unroll
        for (int u = 0; u < 8; ++u) w[u] = vp[(size_t)(tb + u) * (D_ / 4)];
#pragma unroll
        for (int u = 0; u < 8; ++u) {
            float wv[4];
            wv[0] = bf2f((unsigned short)w[u].x);
            wv[1] = bf2f((unsigned short)(w[u].x >> 16));
            wv[2] = bf2f((unsigned short)w[u].y);
            wv[3] = bf2f((unsigned short)(w[u].y >> 16));
#pragma unroll
            for (int k = 0; k < 4; ++k) {
                ar[k] = fmaf(wv[k], c[k], ar[k]);
                ai[k] = fmaf(wv[k], s[k], ai[k]);
                float nc = c[k] * cf[k] - s[k] * sf[k];
                float ns = s[k] * cf[k] + c[k] * sf[k];
                c[k] = nc; s[k] = ns;
            }
        }
    }
    float4* cp = (float4*)(csum + (((size_t)b * NCHUNK_ + chunk) * D_ + d0) * 2);
    float4 o0, o1;
    o0.x = ar[0]; o0.y = ai[0]; o0.z = ar[1]; o0.w = ai[1];
    o1.x = ar[2]; o1.y = ai[2]; o1.z = ar[3]; o1.w = ai[3];
    cp[0] = o0; cp[1] = o1;
}

// Pass 2: exclusive prefix of chunk sums per (b,d); 32-deep batches.
__global__ __launch_bounds__(256) void scan_pass2(float* __restrict__ csum) {
    const int g = blockIdx.x * 256 + threadIdx.x;  // 0 .. B*D-1
    const int b = g / D_;
    const int d = g % D_;
    float2* cs = (float2*)csum;
    const size_t base = (size_t)b * NCHUNK_ * D_ + d;
    float pr = 0.f, pi = 0.f;
    for (int cc = 0; cc < NCHUNK_; cc += 32) {
        float2 buf[32];
#pragma unroll
        for (int k = 0; k < 32; ++k) buf[k] = cs[base + (size_t)(cc + k) * D_];
#pragma unroll
        for (int k = 0; k < 32; ++k) {
            float r = buf[k].x, im = buf[k].y;
            buf[k] = make_float2(pr, pi);
            pr += r; pi += im;
        }
#pragma unroll
        for (int k = 0; k < 32; ++k) cs[base + (size_t)(cc + k) * D_] = buf[k];
    }
}

// Pass 3: replay chunk; retrieved = Re(mt * conj(rotor)) -> bf16; 4 d's/thread.
__global__ __launch_bounds__(256) void scan_pass3(const unsigned short* __restrict__ v,
                                                  const float* __restrict__ freqs,
                                                  const float* __restrict__ csum,
                                                  unsigned short* __restrict__ ret) {
    const int d0 = threadIdx.x * 4;
    const int chunk = blockIdx.x;
    const int b = blockIdx.y;

    float fr[4], s[4], c[4], sf[4], cf[4], ar[4], ai[4];
    {
        float4 f4 = *(const float4*)(freqs + d0);
        fr[0] = f4.x; fr[1] = f4.y; fr[2] = f4.z; fr[3] = f4.w;
    }
    const float t0f = (float)(chunk * CS_);
#pragma unroll
    for (int k = 0; k < 4; ++k) {
        sincosf(t0f * fr[k], &s[k], &c[k]);
        sincosf(fr[k], &sf[k], &cf[k]);
    }
    {
        const float4* cp = (const float4*)(csum + (((size_t)b * NCHUNK_ + chunk) * D_ + d0) * 2);
        float4 o0 = cp[0], o1 = cp[1];
        ar[0] = o0.x; ai[0] = o0.y; ar[1] = o0.z; ai[1] = o0.w;
        ar[2] = o1.x; ai[2] = o1.y; ar[3] = o1.z; ai[3] = o1.w;
    }
    const uint2* vp = (const uint2*)(v + ((size_t)b * T_ + chunk * CS_) * D_ + d0);
    uint2* rp = (uint2*)(ret + ((size_t)b * T_ + chunk * CS_) * D_ + d0);
    for (int tb = 0; tb < CS_; tb += 8) {
        uint2 w[8];
#pragma unroll
        for (int u = 0; u < 8; ++u) w[u] = vp[(size_t)(tb + u) * (D_ / 4)];
#pragma unroll
        for (int u = 0; u < 8; ++u) {
            float wv[4], o[4];
            wv[0] = bf2f((unsigned short)w[u].x);
            wv[1] = bf2f((unsigned short)(w[u].x >> 16));
            wv[2] = bf2f((unsigned short)w[u].y);
            wv[3] = bf2f((unsigned short)(w[u].y >> 16));
#pragma unroll
            for (int k = 0; k < 4; ++k) {
                ar[k] = fmaf(wv[k], c[k], ar[k]);
                ai[k] = fmaf(wv[k], s[k], ai[k]);
                o[k] = ar[k] * c[k] + ai[k] * s[k];   // Re(mt * (cos - i sin))
                float nc = c[k] * cf[k] - s[k] * sf[k];
                float ns = s[k] * cf[k] + c[k] * sf[k];
                c[k] = nc; s[k] = ns;
            }
            uint2 o2;
            o2.x = (unsigned int)f2bf(o[0]) | ((unsigned int)f2bf(o[1]) << 16);
            o2.y = (unsigned int)f2bf(o[2]) | ((unsigned int)f2bf(o[3]) << 16);
            rp[(size_t)(tb + u) * (D_ / 4)] = o2;
        }
    }
}

extern "C" void kernel_launch(void* const* d_in, const int* in_sizes, int n_in,
                              void* d_out, int out_size, void* d_ws, size_t ws_size,
                              hipStream_t stream) {
    const float* x     = (const float*)d_in[0];
    // d_in[1] = Wk (dead in reference)
    const float* Wv    = (const float*)d_in[2];
    const float* Wo    = (const float*)d_in[3];
    const float* freqs = (const float*)d_in[4];
    float* out = (float*)d_out;

    char* ws = (char*)d_ws;
    unsigned short* x_bf  = (unsigned short*)ws;                 // 33,554,432 B
    unsigned short* Wv_bf = (unsigned short*)(ws + 33554432);    //  2,097,152 B
    unsigned short* Wo_bf = (unsigned short*)(ws + 35651584);    //  2,097,152 B
    unsigned short* ret   = (unsigned short*)(ws + 37748736);    // 33,554,432 B
    float*          csum  = (float*)(ws + 71303168);             //  4,194,304 B (B*256*D*2*4)
    // v (bf16) lives in d_out's first half; dead before GEMM2 overwrites d_out.
    unsigned short* v_bf = (unsigned short*)d_out;

    // 1. fused casts (x | Wv | Wo)
    cast_all<<<(BT_ * D_ / 4 + 2 * D_ * D_ / 4) / 256, 256, 0, stream>>>(
        x, Wv, Wo, x_bf, Wv_bf, Wo_bf);

    // 2. v = x @ Wv^T  (bf16 out), XCD-swizzled 1-D grid
    gemm_bt<true><<<(BT_ / 128) * (D_ / 128), 256, 0, stream>>>(
        (const short*)x_bf, (const short*)Wv_bf, (void*)v_bf, BT_, D_, D_);

    // 3. blocked rotor scan
    dim3 sgrid(NCHUNK_, B_);
    scan_pass1<<<sgrid, 256, 0, stream>>>(v_bf, freqs, csum);
    scan_pass2<<<(B_ * D_) / 256, 256, 0, stream>>>(csum);
    scan_pass3<<<sgrid, 256, 0, stream>>>(v_bf, freqs, csum, ret);

    // 4. out = retrieved @ Wo^T (fp32 out), XCD-swizzled 1-D grid
    gemm_bt<false><<<(BT_ / 128) * (D_ / 128), 256, 0, stream>>>(
        (const short*)ret, (const short*)Wo_bf, (void*)out, BT_, D_, D_);
}

// Round 6
// 240.333 us; speedup vs baseline: 1.1732x; 1.0707x over previous
//
#include <hip/hip_runtime.h>
#include <hip/hip_bf16.h>

// HoloAttention: out = (Re(cumsum_t(x@Wv^T * e^{i t f}) * e^{-i t f})) @ Wo^T
// (k-projection in reference is dead code — skipped.)
//
// R6: pass1 fused into GEMM1 epilogue (tile rows == 2 t-chunks of 64; chunk
// sums computed from fp32 acc via incremental rotors + shfl_xor reduce).
// Kernel chain is now cast -> gemm1(+sums) -> pass2 -> pass3 -> gemm2.

#define B_  2
#define T_  8192
#define D_  1024
#define BT_ 16384
#define CS_ 64
#define NCHUNK_ 128

typedef __attribute__((ext_vector_type(4))) float f32x4;
typedef __attribute__((ext_vector_type(8))) short bf16x8;

static __device__ inline unsigned short f2bf(float f) {
    union { float f; unsigned int u; } a;
    a.f = f;
    unsigned int u = a.u;
    return (unsigned short)((u + 0x7FFFu + ((u >> 16) & 1u)) >> 16);  // RNE
}
static __device__ inline float bf2f(unsigned short h) {
    union { unsigned int u; float f; } a;
    a.u = ((unsigned int)h) << 16;
    return a.f;
}

// One fused cast: x (4194304 float4) | Wv (262144) | Wo (262144)
__global__ __launch_bounds__(256) void cast_all(const float* __restrict__ x,
                                                const float* __restrict__ Wv,
                                                const float* __restrict__ Wo,
                                                unsigned short* __restrict__ xb,
                                                unsigned short* __restrict__ wvb,
                                                unsigned short* __restrict__ wob) {
    const int nx = BT_ * D_ / 4;
    const int nw = D_ * D_ / 4;
    int i = blockIdx.x * 256 + threadIdx.x;
    const float4* src;
    unsigned short* dst;
    int j;
    if (i < nx)            { src = (const float4*)x;  dst = xb;  j = i; }
    else if (i < nx + nw)  { src = (const float4*)Wv; dst = wvb; j = i - nx; }
    else                   { src = (const float4*)Wo; dst = wob; j = i - nx - nw; }
    float4 v = src[j];
    ushort4 o;
    o.x = f2bf(v.x); o.y = f2bf(v.y); o.z = f2bf(v.z); o.w = f2bf(v.w);
    ((ushort4*)dst)[j] = o;
}

// C[M,N] = A[M,K] (bf16 row-major) @ Bm[N,K]^T (bf16 row-major).
// 4 waves (2x2), wave tile 64x64 (4x4 mfma 16x16x32), block tile 128x128,
// BK=64 (32 KB LDS), global_load_lds width=16, XCD-swizzled 1-D grid,
// XOR-swizzled LDS columns. FUSE_SUMS (GEMM1): epilogue also emits per-chunk
// rotor sums csum[b][chunk][d] from the fp32 accumulators (wave wr covers
// chunk half wr; cross-lane-group reduce via shfl_xor 16/32).
template <bool BF16OUT, bool FUSE_SUMS>
__global__ __launch_bounds__(256) void gemm_bt(const short* __restrict__ A,
                                               const short* __restrict__ Bm,
                                               void* __restrict__ Cout,
                                               const float* __restrict__ freqs,
                                               float* __restrict__ csum,
                                               int M, int N, int K) {
    __shared__ short lds[16384];  // A tile shorts [0,8192), B tile [8192,16384)
    const int lane = threadIdx.x & 63;
    const int wave = threadIdx.x >> 6;
    const int wr = wave >> 1, wc = wave & 1;

    const int nb = N >> 7;              // N-blocks (8)
    const int id = blockIdx.x;
    const int xcd = id & 7;
    const int slot = id >> 3;
    const int bn = (slot % nb) * 128;
    const int bm = (xcd * ((M >> 7) >> 3) + slot / nb) * 128;

    // staging: 16 chunks of 1 KB per matrix (chunk = 8 rows x 64 cols)
    const int sr = lane >> 3;   // 0..7
    const int cb = lane & 7;    // 0..7
    const short* ga[4];
    const short* gb[4];
#pragma unroll
    for (int cc = 0; cc < 4; ++cc) {
        const int chunk = wave * 4 + cc;
        const int row = chunk * 8 + sr;
        const int col = (cb ^ (row & 7)) * 8;
        ga[cc] = A + (size_t)(bm + row) * K + col;
        gb[cc] = Bm + (size_t)(bn + row) * K + col;
    }

    const int c4r = lane >> 4;  // 0..3
    int aoff[4][2], boff[4][2];
#pragma unroll
    for (int i = 0; i < 4; ++i) {
        const int m = wr * 64 + (lane & 15) + i * 16;
        const int n = wc * 64 + (lane & 15) + i * 16;
#pragma unroll
        for (int ks = 0; ks < 2; ++ks) {
            aoff[i][ks] = m * 64 + (((ks * 4 + c4r) ^ (m & 7)) * 8);
            boff[i][ks] = 8192 + n * 64 + (((ks * 4 + c4r) ^ (n & 7)) * 8);
        }
    }

    f32x4 acc[4][4] = {};

    for (int k0 = 0; k0 < K; k0 += 64) {
#pragma unroll
        for (int cc = 0; cc < 4; ++cc) {
            const int chunk = wave * 4 + cc;
            __builtin_amdgcn_global_load_lds(
                (const __attribute__((address_space(1))) void*)(ga[cc] + k0),
                (__attribute__((address_space(3))) void*)&lds[chunk * 512], 16, 0, 0);
            __builtin_amdgcn_global_load_lds(
                (const __attribute__((address_space(1))) void*)(gb[cc] + k0),
                (__attribute__((address_space(3))) void*)&lds[8192 + chunk * 512], 16, 0, 0);
        }
        __syncthreads();
#pragma unroll
        for (int ks = 0; ks < 2; ++ks) {
            bf16x8 a[4], b[4];
#pragma unroll
            for (int i = 0; i < 4; ++i) a[i] = *(const bf16x8*)&lds[aoff[i][ks]];
#pragma unroll
            for (int j = 0; j < 4; ++j) b[j] = *(const bf16x8*)&lds[boff[j][ks]];
#pragma unroll
            for (int i = 0; i < 4; ++i)
#pragma unroll
                for (int j = 0; j < 4; ++j)
                    acc[i][j] = __builtin_amdgcn_mfma_f32_16x16x32_bf16(a[i], b[j], acc[i][j], 0, 0, 0);
        }
        __syncthreads();
    }

    const int row0 = c4r * 4;
#pragma unroll
    for (int i = 0; i < 4; ++i) {
#pragma unroll
        for (int j = 0; j < 4; ++j) {
            const int col = bn + wc * 64 + j * 16 + (lane & 15);
#pragma unroll
            for (int r = 0; r < 4; ++r) {
                const size_t row = bm + wr * 64 + i * 16 + row0 + r;
                if constexpr (BF16OUT)
                    ((unsigned short*)Cout)[row * N + col] = f2bf(acc[i][j][r]);
                else
                    ((float*)Cout)[row * N + col] = acc[i][j][r];
            }
        }
    }

    if constexpr (FUSE_SUMS) {
        // This wave covers t-chunk (trow>>6)+wr fully for cols bn..bn+127.
        const int b = bm >> 13;
        const int trow = bm & 8191;
        const int chunk = (trow >> 6) + wr;
        const int t0 = trow + wr * 64 + c4r * 4;   // absolute t at i=0,r=0
#pragma unroll
        for (int j = 0; j < 4; ++j) {
            const int d = bn + wc * 64 + j * 16 + (lane & 15);
            const float f = freqs[d];
            float ss, cc2;
            sincosf((float)t0 * f, &ss, &cc2);
            float s1, c1;
            sincosf(f, &s1, &c1);
            // e13 = e1^13 via squarings (rows step +1 within r, +13 across i)
            float c2 = c1 * c1 - s1 * s1, s2 = 2.f * c1 * s1;
            float c4 = c2 * c2 - s2 * s2, s4 = 2.f * c2 * s2;
            float c8 = c4 * c4 - s4 * s4, s8 = 2.f * c4 * s4;
            float c12 = c8 * c4 - s8 * s4, s12 = s8 * c4 + c8 * s4;
            float c13 = c12 * c1 - s12 * s1, s13 = s12 * c1 + c12 * s1;
            float ar = 0.f, ai = 0.f;
            float cr = cc2, sr2 = ss;
#pragma unroll
            for (int i = 0; i < 4; ++i) {
#pragma unroll
                for (int r = 0; r < 4; ++r) {
                    const float w = acc[i][j][r];
                    ar = fmaf(w, cr, ar); ai = fmaf(w, sr2, ai);
                    const float ec = (r < 3) ? c1 : c13;
                    const float es = (r < 3) ? s1 : s13;
                    const float nc = cr * ec - sr2 * es;
                    const float ns = sr2 * ec + cr * es;
                    cr = nc; sr2 = ns;
                }
            }
            ar += __shfl_xor(ar, 16); ai += __shfl_xor(ai, 16);
            ar += __shfl_xor(ar, 32); ai += __shfl_xor(ai, 32);
            if (c4r == 0)
                *(float2*)(csum + (((size_t)b * NCHUNK_ + chunk) * D_ + d) * 2) =
                    make_float2(ar, ai);
        }
    }
}

// Pass 2: exclusive prefix of chunk sums per (b,d); 32-deep batches.
__global__ __launch_bounds__(256) void scan_pass2(float* __restrict__ csum) {
    const int g = blockIdx.x * 256 + threadIdx.x;  // 0 .. B*D-1
    const int b = g / D_;
    const int d = g % D_;
    float2* cs = (float2*)csum;
    const size_t base = (size_t)b * NCHUNK_ * D_ + d;
    float pr = 0.f, pi = 0.f;
    for (int cc = 0; cc < NCHUNK_; cc += 32) {
        float2 buf[32];
#pragma unroll
        for (int k = 0; k < 32; ++k) buf[k] = cs[base + (size_t)(cc + k) * D_];
#pragma unroll
        for (int k = 0; k < 32; ++k) {
            float r = buf[k].x, im = buf[k].y;
            buf[k] = make_float2(pr, pi);
            pr += r; pi += im;
        }
#pragma unroll
        for (int k = 0; k < 32; ++k) cs[base + (size_t)(cc + k) * D_] = buf[k];
    }
}

// Pass 3: replay chunk; retrieved = Re(mt * conj(rotor)) -> bf16; 2 d's/thread,
// CS=64, 8-row load batches, grid (NCHUNK, D/512, B) = 2048 waves.
__global__ __launch_bounds__(256) void scan_pass3(const unsigned short* __restrict__ v,
                                                  const float* __restrict__ freqs,
                                                  const float* __restrict__ csum,
                                                  unsigned short* __restrict__ ret) {
    const int chunk = blockIdx.x;
    const int d0 = blockIdx.y * 512 + threadIdx.x * 2;
    const int b = blockIdx.z;

    float fr[2], s[2], c[2], sf[2], cf[2], ar[2], ai[2];
    {
        float2 f2 = *(const float2*)(freqs + d0);
        fr[0] = f2.x; fr[1] = f2.y;
    }
    const float t0f = (float)(chunk * CS_);
#pragma unroll
    for (int k = 0; k < 2; ++k) {
        sincosf(t0f * fr[k], &s[k], &c[k]);
        sincosf(fr[k], &sf[k], &cf[k]);
    }
    {
        const float4 o = *(const float4*)(csum + (((size_t)b * NCHUNK_ + chunk) * D_ + d0) * 2);
        ar[0] = o.x; ai[0] = o.y; ar[1] = o.z; ai[1] = o.w;
    }
    const unsigned int* vp = (const unsigned int*)(v + ((size_t)b * T_ + chunk * CS_) * D_ + d0);
    unsigned int* rp = (unsigned int*)(ret + ((size_t)b * T_ + chunk * CS_) * D_ + d0);
    for (int tb = 0; tb < CS_; tb += 8) {
        unsigned int w[8];
#pragma unroll
        for (int u = 0; u < 8; ++u) w[u] = vp[(size_t)(tb + u) * (D_ / 2)];
#pragma unroll
        for (int u = 0; u < 8; ++u) {
            float wv[2], o[2];
            wv[0] = bf2f((unsigned short)w[u]);
            wv[1] = bf2f((unsigned short)(w[u] >> 16));
#pragma unroll
            for (int k = 0; k < 2; ++k) {
                ar[k] = fmaf(wv[k], c[k], ar[k]);
                ai[k] = fmaf(wv[k], s[k], ai[k]);
                o[k] = ar[k] * c[k] + ai[k] * s[k];   // Re(mt * (cos - i sin))
                float nc = c[k] * cf[k] - s[k] * sf[k];
                float ns = s[k] * cf[k] + c[k] * sf[k];
                c[k] = nc; s[k] = ns;
            }
            rp[(size_t)(tb + u) * (D_ / 2)] =
                (unsigned int)f2bf(o[0]) | ((unsigned int)f2bf(o[1]) << 16);
        }
    }
}

extern "C" void kernel_launch(void* const* d_in, const int* in_sizes, int n_in,
                              void* d_out, int out_size, void* d_ws, size_t ws_size,
                              hipStream_t stream) {
    const float* x     = (const float*)d_in[0];
    // d_in[1] = Wk (dead in reference)
    const float* Wv    = (const float*)d_in[2];
    const float* Wo    = (const float*)d_in[3];
    const float* freqs = (const float*)d_in[4];
    float* out = (float*)d_out;

    char* ws = (char*)d_ws;
    unsigned short* x_bf  = (unsigned short*)ws;                 // 33,554,432 B
    unsigned short* Wv_bf = (unsigned short*)(ws + 33554432);    //  2,097,152 B
    unsigned short* Wo_bf = (unsigned short*)(ws + 35651584);    //  2,097,152 B
    unsigned short* ret   = (unsigned short*)(ws + 37748736);    // 33,554,432 B
    float*          csum  = (float*)(ws + 71303168);             //  2,097,152 B (B*128*D*2*4)
    // v (bf16) lives in d_out's first half; dead before GEMM2 overwrites d_out.
    unsigned short* v_bf = (unsigned short*)d_out;

    // 1. fused casts (x | Wv | Wo)
    cast_all<<<(BT_ * D_ / 4 + 2 * D_ * D_ / 4) / 256, 256, 0, stream>>>(
        x, Wv, Wo, x_bf, Wv_bf, Wo_bf);

    // 2. v = x @ Wv^T (bf16 out) + fused per-chunk rotor sums
    gemm_bt<true, true><<<(BT_ / 128) * (D_ / 128), 256, 0, stream>>>(
        (const short*)x_bf, (const short*)Wv_bf, (void*)v_bf, freqs, csum, BT_, D_, D_);

    // 3. exclusive prefix over chunks, then replay+unbind
    scan_pass2<<<(B_ * D_) / 256, 256, 0, stream>>>(csum);
    dim3 p3grid(NCHUNK_, D_ / 512, B_);
    scan_pass3<<<p3grid, 256, 0, stream>>>(v_bf, freqs, csum, ret);

    // 4. out = retrieved @ Wo^T (fp32 out)
    gemm_bt<false, false><<<(BT_ / 128) * (D_ / 128), 256, 0, stream>>>(
        (const short*)ret, (const short*)Wo_bf, (void*)out, nullptr, nullptr, BT_, D_, D_);
}